// Round 6
// baseline (406.887 us; speedup 1.0000x reference)
//
#include <hip/hip_runtime.h>
#include <math.h>

// Problem constants
#define NVEC   65536      // B*H*W
#define CDIM   64
#define KBOOK  1024
#define NTOT   4194304    // B*C*H*W

// d_out layout (float32): [quantized_z: NTOT][quantized_z_st: NTOT][indices: NVEC][perplexity: 1]
// workspace (532480 B, fixed): result u32[NVEC] @0 (256KB) ; free @262144 ;
//                              float se[KBOOK] @524288 ; int hist[KBOOK] @528384
// TRANSIENT scratch in d_out's quantized_z region (read only BEFORE scatter overwrites):
//   cbT fp16[64 tiles][1024] @out+1MB (128KB)  -- fragment-ordered, e scaled x2^14
//   aux @out+1.5MB: wcount u32 @+0 ; semax4 f32[4] @+16 ; se16 f32[1024] @+4096 (scaled se)
//   wlist u32[NVEC] @out+2MB (256KB)
// Ordering: prep -> approx(decisive ns finalized) -> rescore2(flagged ns, exact full search)
//           -> scatter(+perp). 4 launches.
//
// ROUND-5 DESIGN (deterministic accuracy contract):
//   approx computes d'(n,k)*2^14 = se_k*2^14 + sum_c fl16(-2z_c)*fl16(e_c*2^14) via ONE
//   fp16 MFMA term (2 MFMA/tile).  Global top-2 per n via packed-u32-key butterflies.
//   If (f2-f1) > THR(n) with THR a WORST-CASE bound on |approx - reference| deviation
//   (fp16 conv 2^-11*Sum|m*e| <= 2^-10*sqrt(sx)*sqrt(semax) by Cauchy-Schwarz, reference
//   chain rounding <= 2*ulp(sx), key truncation 1024*ulp, accum/denorm slack, x1.25),
//   the approx argmin PROVABLY equals the reference argmin -> finalize directly.
//   Else: exact full 1024-k rescore (bit-identical reference chain).  No probabilistic
//   candidate-containment assumption remains.

typedef _Float16 f16x8 __attribute__((ext_vector_type(8)));
typedef float    f32x4 __attribute__((ext_vector_type(4)));

// prep: zero hist/wcount; exact se (pairwise 8-acc, rn intrinsics); se16 = se*2^14;
// semax4[block] = block-max of se; pack fragment-ordered fp16 codebook (e*2^14).
__global__ void prep_kernel(const float* __restrict__ cb, float* __restrict__ se,
                            int* __restrict__ hist, _Float16* __restrict__ cbT,
                            float* __restrict__ se16, float* __restrict__ semax4,
                            unsigned* __restrict__ wcount) {
    __shared__ float lmax[4];
    const int t = blockIdx.x * 256 + threadIdx.x;   // grid 4x256 -> t = codebook row k
    if (t == 0) *wcount = 0u;
    hist[t] = 0;
    const float* row = cb + t * CDIM;
    float r[8];
#pragma unroll
    for (int j = 0; j < 8; ++j) r[j] = __fmul_rn(row[j], row[j]);
#pragma unroll
    for (int i = 8; i < 64; i += 8)
#pragma unroll
        for (int j = 0; j < 8; ++j) r[j] = __fadd_rn(r[j], __fmul_rn(row[i + j], row[i + j]));
    const float sev = __fadd_rn(__fadd_rn(__fadd_rn(r[0], r[1]), __fadd_rn(r[2], r[3])),
                                __fadd_rn(__fadd_rn(r[4], r[5]), __fadd_rn(r[6], r[7])));
    se[t] = sev;
    se16[t] = sev * 16384.0f;            // exact (x2^14)
    // block max of se -> semax4
    float m = sev;
#pragma unroll
    for (int off = 32; off > 0; off >>= 1) m = fmaxf(m, __shfl_xor(m, off));
    if ((threadIdx.x & 63) == 0) lmax[threadIdx.x >> 6] = m;
    __syncthreads();
    if (threadIdx.x == 0)
        semax4[blockIdx.x] = fmaxf(fmaxf(lmax[0], lmax[1]), fmaxf(lmax[2], lmax[3]));
    // fragment-ordered fp16 codebook, scaled: sub[lane*8+j] = fl16(e*2^14)
    const int tt = t >> 4, la = t & 15;
    _Float16* tb = cbT + (size_t)tt * 1024;        // 2KB tile block (fp16 units)
#pragma unroll
    for (int g = 0; g < 4; ++g)
#pragma unroll
        for (int j = 0; j < 8; ++j) {
            const float e0 = row[8 * g + j] * 16384.0f;        // c in [0,32)
            const float e1 = row[32 + 8 * g + j] * 16384.0f;   // c in [32,64)
            const int lo8 = (g * 16 + la) * 8 + j;             // lane*8 + j
            tb[lo8]       = (_Float16)e0;                      // ah0
            tb[512 + lo8] = (_Float16)e1;                      // ah1
        }
}

// MFMA approx + margin filter.  B-frag: lane holds B[8*(l>>4)+j][l&15];
// D: col = l&15 (n), row = 4*(l>>4)+reg (k).  Per-lane top-2 over its 256-k subset as
// packed keys (truncated ordered-float d' | k); 2 shfl_xor butterflies -> exact global
// top-2 (top-2-of-subsets merge is exact).  Decisive -> finalize; else -> worklist.
__launch_bounds__(256)
__attribute__((amdgpu_waves_per_eu(4, 4)))
__global__ void approx_kernel(const float* __restrict__ z, const _Float16* __restrict__ cbT,
                              const float* __restrict__ se16, const float* __restrict__ semax4,
                              unsigned* __restrict__ result, unsigned* __restrict__ wlist,
                              unsigned* __restrict__ wcount, float* __restrict__ outIdxF,
                              int* __restrict__ hist) {
    const int tid = threadIdx.x;
    const int w = tid >> 6;           // wave in block
    const int l = tid & 63;           // lane
    const int la = l & 15;            // D-col (n) offset / A-row offset
    const int g  = l >> 4;            // lane group
    const int n = blockIdx.x * 64 + w * 16 + la;
    const int b = n >> 10, hw = n & 1023;
    const float* zb = z + (size_t)b * (CDIM * 1024) + hw;   // + c*1024

    // B-fragments: m = -2z in fp16 (exact -2z in fp32, then RNE fp16).
    // psum = this lane's partial sum of z^2 over its 16 c's (for THR only).
    f16x8 mh0, mh1;
    float psum = 0.0f;
#pragma unroll
    for (int j = 0; j < 8; ++j) {
        {   float zc = zb[(g * 8 + j) * 1024];
            mh0[j] = (_Float16)(-2.0f * zc);
            psum = fmaf(zc, zc, psum); }
        {   float zc = zb[(32 + g * 8 + j) * 1024];
            mh1[j] = (_Float16)(-2.0f * zc);
            psum = fmaf(zc, zc, psum); }
    }

    unsigned u1k = 0xFFFFFFFFu, u2k = 0xFFFFFFFFu;
    const int kv = g * 4;                          // D-row base for this lane
    const _Float16* tbase = cbT + (size_t)l * 8;   // lane offset inside each sub-block

#define DECL_SLOT(s) f16x8 ah0_##s, ah1_##s; f32x4 se_##s;
    DECL_SLOT(a) DECL_SLOT(b) DECL_SLOT(c) DECL_SLOT(d)
#undef DECL_SLOT

    // tile-slot load: 2 contiguous 1KB wave-loads + 16B se16 ('& 63' wraps overshoot)
#define LOADT(s, ttv) { const int t_ = (ttv) & 63;                       \
        const _Float16* p_ = tbase + (size_t)t_ * 1024;                  \
        ah0_##s = *(const f16x8*)(p_);                                   \
        ah1_##s = *(const f16x8*)(p_ + 512);                             \
        se_##s  = *(const f32x4*)(se16 + t_ * 16 + kv); }

    // pack (truncated ordered-float | k) + 3-op top-2 insert
#define PINS(acc_, r_, k0_) {                                            \
        unsigned ub = __float_as_uint(acc_[r_]);                         \
        ub = ((int)ub < 0) ? ~ub : (ub | 0x80000000u);                   \
        const unsigned key = (ub & 0xFFFFFC00u) | (unsigned)((k0_) + kv + (r_)); \
        const unsigned mx = (u1k > key) ? u1k : key;                     \
        u1k = (u1k < key) ? u1k : key;                                   \
        u2k = (u2k < mx) ? u2k : mx; }

#define COMPT(s, ttv) { const int k0_ = (ttv) * 16;                      \
        f32x4 acc = se_##s;                                              \
        acc = __builtin_amdgcn_mfma_f32_16x16x32_f16(ah0_##s, mh0, acc, 0, 0, 0); \
        acc = __builtin_amdgcn_mfma_f32_16x16x32_f16(ah1_##s, mh1, acc, 0, 0, 0); \
        PINS(acc, 0, k0_) PINS(acc, 1, k0_) PINS(acc, 2, k0_) PINS(acc, 3, k0_) }

    LOADT(a, 0) LOADT(b, 1)
    for (int tt = 0; tt < 64; tt += 4) {
        LOADT(c, tt + 2) LOADT(d, tt + 3)
        COMPT(a, tt)     COMPT(b, tt + 1)
        LOADT(a, tt + 4) LOADT(b, tt + 5)
        COMPT(c, tt + 2) COMPT(d, tt + 3)
    }
#undef LOADT
#undef PINS
#undef COMPT

    // exact global top-2 + full-sum-of-z^2 across the 4 same-n lanes (xor 16, 32)
#pragma unroll
    for (int off = 16; off <= 32; off <<= 1) {
        const unsigned p1 = __shfl_xor(u1k, off);
        const unsigned p2 = __shfl_xor(u2k, off);
        psum += __shfl_xor(psum, off);
        const unsigned mx = (u1k > p1) ? u1k : p1;
        u1k = (u1k < p1) ? u1k : p1;
        const unsigned m2 = (u2k < p2) ? u2k : p2;
        u2k = (m2 < mx) ? m2 : mx;
    }

    if (l < 16) {
        const float sx = psum;
        const float srt = sqrtf(fmaxf(fmaxf(semax4[0], semax4[1]),
                                      fmaxf(semax4[2], semax4[3]))) * 1.0001f;
        // worst-case deviation bound (scaled x2^14 space), x1.25 slack:
        //   2*(2^-11*2*sqrt(sx)*srt [fp16 conv, C-S] + 2*ulp(sx) [ref rounding] + 4e-6)
        //   + 2*1024*ulp(|d'|max) [key truncation]
        const float THR = 60.2f * sqrtf(sx) * srt + 1.97e-2f * sx + 0.165f;
        const unsigned x1 = u1k & 0xFFFFFC00u, x2 = u2k & 0xFFFFFC00u;
        const float f1 = __uint_as_float((x1 & 0x80000000u) ? (x1 & 0x7FFFFFFFu) : ~x1);
        const float f2 = __uint_as_float((x2 & 0x80000000u) ? (x2 & 0x7FFFFFFFu) : ~x2);
        const int k1 = (int)(u1k & 1023u);
        if (f2 - f1 > THR) {     // unique exact argmin guaranteed
            result[n] = (unsigned)k1;
            outIdxF[n] = (float)k1;
            atomicAdd(&hist[k1], 1);
        } else {
            const unsigned widx = atomicAdd(wcount, 1u);
            wlist[widx] = (unsigned)n;
        }
    }
}

// Exact full 1024-k search for flagged n.  Bit-identical chain to the reference:
// zx = 2z; a_k = ascending-c fmaf chain; sx = pairwise 8-acc of fl(z^2);
// d = fl(fl(sx + se_k) - a_k).  16 lanes per n (64 k each); u64 ordered-key min
// (d bits || k) gives first-min semantics.
__launch_bounds__(256)
__global__ void rescore2_kernel(const float* __restrict__ z, const float* __restrict__ cb,
                                const float* __restrict__ se,
                                const unsigned* __restrict__ wlist,
                                const unsigned* __restrict__ wcount,
                                unsigned* __restrict__ result, int* __restrict__ hist,
                                float* __restrict__ outIdxF) {
    const int cnt = (int)*wcount;
    const int tid = threadIdx.x;
    const int wv = tid >> 6, l = tid & 63;
    const int base = (blockIdx.x * 4 + wv) * 4;     // first item of this wave (4 n/wave)
    if (base >= cnt) return;
    const int s = l >> 4, j = l & 15;
    const int item = base + s;
    const int n = (int)wlist[(item < cnt) ? item : base];   // dup-safe dummy for tail
    const int b = n >> 10, hw = n & 1023;
    const float* zb = z + (size_t)b * (CDIM * 1024) + hw;

    float zx[64], r[8];
#pragma unroll
    for (int jj = 0; jj < 8; ++jj) {
        const float zc = zb[jj * 1024];
        zx[jj] = zc + zc;
        r[jj] = __fmul_rn(zc, zc);
    }
#pragma unroll
    for (int c = 8; c < 64; ++c) {
        const float zc = zb[c * 1024];
        zx[c] = zc + zc;
        r[c & 7] = __fadd_rn(r[c & 7], __fmul_rn(zc, zc));
    }
    const float sx = __fadd_rn(__fadd_rn(__fadd_rn(r[0], r[1]), __fadd_rn(r[2], r[3])),
                               __fadd_rn(__fadd_rn(r[4], r[5]), __fadd_rn(r[6], r[7])));

    unsigned long long best = ~0ull;
    const float4* cb4 = (const float4*)cb;
    const int kb0 = j * 64;
    for (int kk = 0; kk < 64; kk += 4) {
        const int k = kb0 + kk;
        float a0 = 0.f, a1 = 0.f, a2 = 0.f, a3 = 0.f;
#pragma unroll
        for (int q = 0; q < 16; ++q) {
            const float4 e0 = cb4[(k + 0) * 16 + q];
            const float4 e1 = cb4[(k + 1) * 16 + q];
            const float4 e2 = cb4[(k + 2) * 16 + q];
            const float4 e3 = cb4[(k + 3) * 16 + q];
            a0 = fmaf(zx[4*q], e0.x, a0); a0 = fmaf(zx[4*q+1], e0.y, a0);
            a0 = fmaf(zx[4*q+2], e0.z, a0); a0 = fmaf(zx[4*q+3], e0.w, a0);
            a1 = fmaf(zx[4*q], e1.x, a1); a1 = fmaf(zx[4*q+1], e1.y, a1);
            a1 = fmaf(zx[4*q+2], e1.z, a1); a1 = fmaf(zx[4*q+3], e1.w, a1);
            a2 = fmaf(zx[4*q], e2.x, a2); a2 = fmaf(zx[4*q+1], e2.y, a2);
            a2 = fmaf(zx[4*q+2], e2.z, a2); a2 = fmaf(zx[4*q+3], e2.w, a2);
            a3 = fmaf(zx[4*q], e3.x, a3); a3 = fmaf(zx[4*q+1], e3.y, a3);
            a3 = fmaf(zx[4*q+2], e3.z, a3); a3 = fmaf(zx[4*q+3], e3.w, a3);
        }
#define DKEY(ai, ki) { const float d_ = __fsub_rn(__fadd_rn(sx, se[ki]), ai);      \
        unsigned ob = __float_as_uint(d_);                                         \
        ob = (ob & 0x80000000u) ? ~ob : (ob | 0x80000000u);                        \
        const unsigned long long key = ((unsigned long long)ob << 32) | (unsigned)(ki); \
        if (key < best) best = key; }
        DKEY(a0, k) DKEY(a1, k + 1) DKEY(a2, k + 2) DKEY(a3, k + 3)
#undef DKEY
    }
    // 16-lane tree min (stays within the 16-lane n-group)
#pragma unroll
    for (int off = 1; off <= 8; off <<= 1) {
        const unsigned long long o = __shfl_xor(best, off);
        if (o < best) best = o;
    }
    if (j == 0 && item < cnt) {
        const int kb = (int)(best & 0xFFFFFFFFull);
        result[n] = (unsigned)kb;
        outIdxF[n] = (float)kb;
        atomicAdd(&hist[kb], 1);
    }
}

// quantized_z = cb[idx]; quantized_z_st = fl(z + fl(q - z)); float4-vectorized.
// Block 0 computes perplexity (hist complete: approx+rescore2 finished, stream order).
__global__ void scatter_kernel(const float* __restrict__ z, const float* __restrict__ cb,
                               const unsigned* __restrict__ result,
                               const int* __restrict__ hist,
                               float* __restrict__ out) {
    const int o = (blockIdx.x * 256 + threadIdx.x) * 4;    // [0, NTOT), step 4
    const int b = o >> 16, c = (o >> 10) & 63, hw = o & 1023;
    const int n = (b << 10) | hw;
    float q[4];
#pragma unroll
    for (int j = 0; j < 4; ++j) {
        const int k = (int)result[n + j];
        q[j] = cb[k * CDIM + c];
    }
    const float4 zv = *(const float4*)(z + o);
    *(float4*)(out + o) = make_float4(q[0], q[1], q[2], q[3]);
    float4 st;
    st.x = __fadd_rn(zv.x, __fsub_rn(q[0], zv.x));
    st.y = __fadd_rn(zv.y, __fsub_rn(q[1], zv.y));
    st.z = __fadd_rn(zv.z, __fsub_rn(q[2], zv.z));
    st.w = __fadd_rn(zv.w, __fsub_rn(q[3], zv.w));
    *(float4*)(out + NTOT + o) = st;

    if (blockIdx.x == 0) {
        __shared__ double partial[4];
        const int t = threadIdx.x;        // 256 threads x 4 hist entries
        double term = 0.0;
#pragma unroll
        for (int j = 0; j < 4; ++j) {
            const int cnt = hist[t + 256 * j];
            if (cnt > 0) { const double p = (double)cnt / (double)NVEC; term += p * log(p); }
        }
        for (int off = 32; off > 0; off >>= 1) term += __shfl_down(term, off);
        if ((t & 63) == 0) partial[t >> 6] = term;
        __syncthreads();
        if (t == 0) {
            const double sm = partial[0] + partial[1] + partial[2] + partial[3];
            out[2 * NTOT + NVEC] = (float)exp(-sm);
        }
    }
}

extern "C" void kernel_launch(void* const* d_in, const int* in_sizes, int n_in,
                              void* d_out, int out_size, void* d_ws, size_t ws_size,
                              hipStream_t stream) {
    const float* z  = (const float*)d_in[0];   // [64,64,32,32]
    const float* cb = (const float*)d_in[1];   // [1024,64]
    float* out = (float*)d_out;

    char* ws = (char*)d_ws;
    unsigned* result = (unsigned*)ws;                      // 256 KB
    float* se   = (float*)(ws + 524288);
    int*   hist = (int*)(ws + 528384);

    // Transient scratch inside d_out's quantized_z region (overwritten by scatter later).
    char* outB = (char*)d_out;
    _Float16* cbT   = (_Float16*)(outB + (1 << 20));       // 128 KB
    unsigned* wcount = (unsigned*)(outB + 1572864);
    float*    semax4 = (float*)(outB + 1572864 + 16);
    float*    se16   = (float*)(outB + 1572864 + 4096);    // 4 KB
    unsigned* wlist  = (unsigned*)(outB + (2 << 20));      // 256 KB

    float* outIdxF = out + 2 * NTOT;

    prep_kernel<<<4, 256, 0, stream>>>(cb, se, hist, cbT, se16, semax4, wcount);
    approx_kernel<<<NVEC / 64, 256, 0, stream>>>(z, cbT, se16, semax4, result, wlist,
                                                 wcount, outIdxF, hist);
    rescore2_kernel<<<NVEC / 16, 256, 0, stream>>>(z, cb, se, wlist, wcount, result,
                                                   hist, outIdxF);
    scatter_kernel<<<NTOT / 1024, 256, 0, stream>>>(z, cb, result, hist, out);
}

// Round 7
// 320.648 us; speedup vs baseline: 1.2690x; 1.2690x over previous
//
#include <hip/hip_runtime.h>
#include <math.h>

// Problem constants
#define NVEC   65536      // B*H*W
#define CDIM   64
#define KBOOK  1024
#define NTOT   4194304    // B*C*H*W

// d_out layout (float32): [quantized_z: NTOT][quantized_z_st: NTOT][indices: NVEC][perplexity: 1]
// workspace: result u32[NVEC] @0 (256KB) ; float se[KBOOK] @524288 ; int hist[KBOOK] @528384
// TRANSIENT scratch in d_out's quantized_z region (read only BEFORE scatter overwrites):
//   cbT fp16[64 tiles][1024] @out+1MB (128KB) -- fragment-ordered, e scaled x2^14
//   aux @out+1.5MB: wcount u32 @+0 ; semax4 f32[4] @+16 ; se16 f32[1024] @+4096
//   wlist u32[NVEC] @out+2MB (256KB)
// Ordering: prep -> approx(decisive finalized) -> rescore2(flagged, exact full search)
//           -> scatter(+perp). 4 launches.
//
// ROUND-6: margin machinery unchanged (validated r5, absmax 0).  Fixes:
//  (1) rescore2 rebuilt: block-per-4-n grid-stride; cb swept once per 4 n;
//      zx/sx staged in LDS via the bit-exact reference chain; u64-key reduce.
//      (r5: 16 lanes/n, 160 VGPR, empty grid -> 256us at 4% efficiency.)
//  (2) approx k-split: wave-pair shares an n-tile, each wave does 512 k;
//      exact top-2 merge in LDS.  8192 waves = 8/SIMD TLP (ILP was exhausted).

typedef _Float16 f16x8 __attribute__((ext_vector_type(8)));
typedef float    f32x4 __attribute__((ext_vector_type(4)));

// prep: zero hist/wcount; exact se (pairwise 8-acc, rn intrinsics); se16 = se*2^14;
// semax4[block] = block-max of se; pack fragment-ordered fp16 codebook (e*2^14).
__global__ void prep_kernel(const float* __restrict__ cb, float* __restrict__ se,
                            int* __restrict__ hist, _Float16* __restrict__ cbT,
                            float* __restrict__ se16, float* __restrict__ semax4,
                            unsigned* __restrict__ wcount) {
    __shared__ float lmax[4];
    const int t = blockIdx.x * 256 + threadIdx.x;   // grid 4x256 -> t = codebook row k
    if (t == 0) *wcount = 0u;
    hist[t] = 0;
    const float* row = cb + t * CDIM;
    float r[8];
#pragma unroll
    for (int j = 0; j < 8; ++j) r[j] = __fmul_rn(row[j], row[j]);
#pragma unroll
    for (int i = 8; i < 64; i += 8)
#pragma unroll
        for (int j = 0; j < 8; ++j) r[j] = __fadd_rn(r[j], __fmul_rn(row[i + j], row[i + j]));
    const float sev = __fadd_rn(__fadd_rn(__fadd_rn(r[0], r[1]), __fadd_rn(r[2], r[3])),
                                __fadd_rn(__fadd_rn(r[4], r[5]), __fadd_rn(r[6], r[7])));
    se[t] = sev;
    se16[t] = sev * 16384.0f;            // exact (x2^14)
    float m = sev;
#pragma unroll
    for (int off = 32; off > 0; off >>= 1) m = fmaxf(m, __shfl_xor(m, off));
    if ((threadIdx.x & 63) == 0) lmax[threadIdx.x >> 6] = m;
    __syncthreads();
    if (threadIdx.x == 0)
        semax4[blockIdx.x] = fmaxf(fmaxf(lmax[0], lmax[1]), fmaxf(lmax[2], lmax[3]));
    const int tt = t >> 4, la = t & 15;
    _Float16* tb = cbT + (size_t)tt * 1024;        // 2KB tile block (fp16 units)
#pragma unroll
    for (int g = 0; g < 4; ++g)
#pragma unroll
        for (int j = 0; j < 8; ++j) {
            const float e0 = row[8 * g + j] * 16384.0f;        // c in [0,32)
            const float e1 = row[32 + 8 * g + j] * 16384.0f;   // c in [32,64)
            const int lo8 = (g * 16 + la) * 8 + j;             // lane*8 + j
            tb[lo8]       = (_Float16)e0;                      // ah0
            tb[512 + lo8] = (_Float16)e1;                      // ah1
        }
}

// MFMA approx + margin filter.  Wave-pair per 16-n tile: wave kh handles k-half
// [kh*512, kh*512+512) (32 tiles); exact top-2 merge across halves via LDS.
// Per-lane top-2 over its 128-k subset (packed truncated-ordered-float | k keys),
// xor-16/32 butterflies -> wave top-2, LDS merge -> global top-2.  Decisive ->
// finalize; else -> worklist.  THR: worst-case |approx - ref| bound (r5, validated).
__launch_bounds__(256)
__attribute__((amdgpu_waves_per_eu(8)))
__global__ void approx_kernel(const float* __restrict__ z, const _Float16* __restrict__ cbT,
                              const float* __restrict__ se16, const float* __restrict__ semax4,
                              unsigned* __restrict__ result, unsigned* __restrict__ wlist,
                              unsigned* __restrict__ wcount, float* __restrict__ outIdxF,
                              int* __restrict__ hist) {
    __shared__ unsigned m1[4][16], m2[4][16];
    const int tid = threadIdx.x;
    const int w = tid >> 6;           // wave in block
    const int l = tid & 63;           // lane
    const int la = l & 15;            // D-col (n) offset / A-row offset
    const int g  = l >> 4;            // lane group
    const int pair = w >> 1;          // n-tile pair in block
    const int kh = w & 1;             // k-half
    const int n = blockIdx.x * 32 + pair * 16 + la;
    const int b = n >> 10, hw = n & 1023;
    const float* zb = z + (size_t)b * (CDIM * 1024) + hw;   // + c*1024

    // B-fragments: m = -2z in fp16 (exact -2z in fp32, then RNE fp16).
    // psum = lane partial sum of z^2 (for THR only).
    f16x8 mh0, mh1;
    float psum = 0.0f;
#pragma unroll
    for (int j = 0; j < 8; ++j) {
        {   float zc = zb[(g * 8 + j) * 1024];
            mh0[j] = (_Float16)(-2.0f * zc);
            psum = fmaf(zc, zc, psum); }
        {   float zc = zb[(32 + g * 8 + j) * 1024];
            mh1[j] = (_Float16)(-2.0f * zc);
            psum = fmaf(zc, zc, psum); }
    }

    unsigned u1k = 0xFFFFFFFFu, u2k = 0xFFFFFFFFu;
    const int kv = g * 4;                          // D-row base for this lane
    const _Float16* tbase = cbT + (size_t)l * 8;   // lane offset inside each sub-block

#define DECL_SLOT(s) f16x8 ah0_##s, ah1_##s; f32x4 se_##s;
    DECL_SLOT(a) DECL_SLOT(b)
#undef DECL_SLOT

#define LOADT(s, ttv) { const int t_ = (ttv) & 63;                       \
        const _Float16* p_ = tbase + (size_t)t_ * 1024;                  \
        ah0_##s = *(const f16x8*)(p_);                                   \
        ah1_##s = *(const f16x8*)(p_ + 512);                             \
        se_##s  = *(const f32x4*)(se16 + t_ * 16 + kv); }

#define PINS(acc_, r_, k0_) {                                            \
        unsigned ub = __float_as_uint(acc_[r_]);                         \
        ub = ((int)ub < 0) ? ~ub : (ub | 0x80000000u);                   \
        const unsigned key = (ub & 0xFFFFFC00u) | (unsigned)((k0_) + kv + (r_)); \
        const unsigned mx = (u1k > key) ? u1k : key;                     \
        u1k = (u1k < key) ? u1k : key;                                   \
        u2k = (u2k < mx) ? u2k : mx; }

#define COMPT(s, ttv) { const int k0_ = (ttv) * 16;                      \
        f32x4 acc = se_##s;                                              \
        acc = __builtin_amdgcn_mfma_f32_16x16x32_f16(ah0_##s, mh0, acc, 0, 0, 0); \
        acc = __builtin_amdgcn_mfma_f32_16x16x32_f16(ah1_##s, mh1, acc, 0, 0, 0); \
        PINS(acc, 0, k0_) PINS(acc, 1, k0_) PINS(acc, 2, k0_) PINS(acc, 3, k0_) }

    const int t0 = kh * 32;
    LOADT(a, t0)
    for (int tt = t0; tt < t0 + 32; tt += 2) {
        LOADT(b, tt + 1)
        COMPT(a, tt)
        LOADT(a, tt + 2)
        COMPT(b, tt + 1)
    }
#undef LOADT
#undef PINS
#undef COMPT

    // wave-level exact top-2 + full sum(z^2) across the 4 same-n lane groups
#pragma unroll
    for (int off = 16; off <= 32; off <<= 1) {
        const unsigned p1 = __shfl_xor(u1k, off);
        const unsigned p2 = __shfl_xor(u2k, off);
        psum += __shfl_xor(psum, off);
        const unsigned mx = (u1k > p1) ? u1k : p1;
        u1k = (u1k < p1) ? u1k : p1;
        const unsigned mm = (u2k < p2) ? u2k : p2;
        u2k = (mm < mx) ? mm : mx;
    }

    if (l < 16) { m1[w][la] = u1k; m2[w][la] = u2k; }
    __syncthreads();

    if (kh == 0 && l < 16) {
        // merge with partner k-half (exact top-2-of-disjoint-subsets merge)
        const unsigned o1 = m1[w + 1][la], o2 = m2[w + 1][la];
        const unsigned mx = (u1k > o1) ? u1k : o1;
        const unsigned u1 = (u1k < o1) ? u1k : o1;
        unsigned u2 = (u2k < o2) ? u2k : o2;
        u2 = (u2 < mx) ? u2 : mx;

        const float sx = psum;
        const float srt = sqrtf(fmaxf(fmaxf(semax4[0], semax4[1]),
                                      fmaxf(semax4[2], semax4[3]))) * 1.0001f;
        // worst-case deviation bound (scaled x2^14 space), x1.25 slack (r5-validated)
        const float THR = 60.2f * sqrtf(sx) * srt + 1.97e-2f * sx + 0.165f;
        const unsigned x1 = u1 & 0xFFFFFC00u, x2 = u2 & 0xFFFFFC00u;
        const float f1 = __uint_as_float((x1 & 0x80000000u) ? (x1 & 0x7FFFFFFFu) : ~x1);
        const float f2 = __uint_as_float((x2 & 0x80000000u) ? (x2 & 0x7FFFFFFFu) : ~x2);
        const int k1 = (int)(u1 & 1023u);
        if (f2 - f1 > THR) {     // unique exact argmin guaranteed
            result[n] = (unsigned)k1;
            outIdxF[n] = (float)k1;
            atomicAdd(&hist[k1], 1);
        } else {
            const unsigned widx = atomicAdd(wcount, 1u);
            wlist[widx] = (unsigned)n;
        }
    }
}

// Exact full 1024-k search for flagged n.  Block per 4 worklist items, grid-stride.
// zx/sx staged in LDS via the bit-identical reference chain; thread t owns k=4t..4t+3
// for ALL 4 n (cb swept once per group); u64 ordered-key (d bits || k) min -> first-min.
__launch_bounds__(256)
__global__ void rescore2_kernel(const float* __restrict__ z, const float* __restrict__ cb,
                                const float* __restrict__ se,
                                const unsigned* __restrict__ wlist,
                                const unsigned* __restrict__ wcount,
                                unsigned* __restrict__ result, int* __restrict__ hist,
                                float* __restrict__ outIdxF) {
    __shared__ float zxs[4][64];
    __shared__ float rres[4][8];
    __shared__ float sxs[4];
    __shared__ unsigned long long red[4][4];   // [wave][n-slot]
    const int cnt = (int)*wcount;
    const int tid = threadIdx.x;
    const int wv = tid >> 6, l = tid & 63;
    const float4* cb4 = (const float4*)cb;

    for (int base = blockIdx.x * 4; base < cnt; base += gridDim.x * 4) {
        // ---- stage: thread = ns*64 + c ----
        const int ns = tid >> 6, c = tid & 63;
        const int item = base + ns;
        const int n = (int)wlist[(item < cnt) ? item : base];   // dup-safe tail
        {
            const int b = n >> 10, hw = n & 1023;
            const float zc = z[(size_t)b * (CDIM * 1024) + c * 1024 + hw];
            zxs[ns][c] = zc + zc;                // exact 2z
        }
        __syncthreads();
        if (c < 8) {                             // 8 residue chains (ref-exact)
            const float z0 = zxs[ns][c] * 0.5f;  // exact recover z
            float rr = __fmul_rn(z0, z0);
            for (int i = c + 8; i < 64; i += 8) {
                const float zi = zxs[ns][i] * 0.5f;
                rr = __fadd_rn(rr, __fmul_rn(zi, zi));
            }
            rres[ns][c] = rr;
        }
        __syncthreads();
        if (c == 0) {
            const float* r = rres[ns];
            sxs[ns] = __fadd_rn(__fadd_rn(__fadd_rn(r[0], r[1]), __fadd_rn(r[2], r[3])),
                                __fadd_rn(__fadd_rn(r[4], r[5]), __fadd_rn(r[6], r[7])));
        }
        __syncthreads();

        // ---- k phase: thread owns k0..k0+3 for all 4 n ----
        const int k0 = tid * 4;
        float acc[4][4];
#pragma unroll
        for (int s2 = 0; s2 < 4; ++s2)
#pragma unroll
            for (int i = 0; i < 4; ++i) acc[s2][i] = 0.0f;
#pragma unroll
        for (int q = 0; q < 16; ++q) {          // ascending c per chain (ref-exact)
            const float4 e0 = cb4[(k0 + 0) * 16 + q];
            const float4 e1 = cb4[(k0 + 1) * 16 + q];
            const float4 e2 = cb4[(k0 + 2) * 16 + q];
            const float4 e3 = cb4[(k0 + 3) * 16 + q];
#pragma unroll
            for (int s2 = 0; s2 < 4; ++s2) {
                const f32x4 zq = *(const f32x4*)&zxs[s2][4 * q];   // LDS broadcast
                acc[s2][0] = fmaf(zq[0], e0.x, acc[s2][0]);
                acc[s2][0] = fmaf(zq[1], e0.y, acc[s2][0]);
                acc[s2][0] = fmaf(zq[2], e0.z, acc[s2][0]);
                acc[s2][0] = fmaf(zq[3], e0.w, acc[s2][0]);
                acc[s2][1] = fmaf(zq[0], e1.x, acc[s2][1]);
                acc[s2][1] = fmaf(zq[1], e1.y, acc[s2][1]);
                acc[s2][1] = fmaf(zq[2], e1.z, acc[s2][1]);
                acc[s2][1] = fmaf(zq[3], e1.w, acc[s2][1]);
                acc[s2][2] = fmaf(zq[0], e2.x, acc[s2][2]);
                acc[s2][2] = fmaf(zq[1], e2.y, acc[s2][2]);
                acc[s2][2] = fmaf(zq[2], e2.z, acc[s2][2]);
                acc[s2][2] = fmaf(zq[3], e2.w, acc[s2][2]);
                acc[s2][3] = fmaf(zq[0], e3.x, acc[s2][3]);
                acc[s2][3] = fmaf(zq[1], e3.y, acc[s2][3]);
                acc[s2][3] = fmaf(zq[2], e3.z, acc[s2][3]);
                acc[s2][3] = fmaf(zq[3], e3.w, acc[s2][3]);
            }
        }

        // ---- reduce: per n-slot u64 key min over 1024 k ----
#pragma unroll
        for (int s2 = 0; s2 < 4; ++s2) {
            unsigned long long best = ~0ull;
#pragma unroll
            for (int i = 0; i < 4; ++i) {
                const int ki = k0 + i;
                const float d = __fsub_rn(__fadd_rn(sxs[s2], se[ki]), acc[s2][i]);
                unsigned ob = __float_as_uint(d);
                ob = (ob & 0x80000000u) ? ~ob : (ob | 0x80000000u);
                const unsigned long long key = ((unsigned long long)ob << 32) | (unsigned)ki;
                if (key < best) best = key;
            }
#pragma unroll
            for (int off = 1; off <= 32; off <<= 1) {
                const unsigned long long o = __shfl_xor(best, off);
                if (o < best) best = o;
            }
            if (l == 0) red[wv][s2] = best;
        }
        __syncthreads();
        if (tid < 4 && base + tid < cnt) {
            unsigned long long bb = red[0][tid];
            if (red[1][tid] < bb) bb = red[1][tid];
            if (red[2][tid] < bb) bb = red[2][tid];
            if (red[3][tid] < bb) bb = red[3][tid];
            const int n2 = (int)wlist[base + tid];
            const int kb = (int)(bb & 0xFFFFFFFFull);
            result[n2] = (unsigned)kb;
            outIdxF[n2] = (float)kb;
            atomicAdd(&hist[kb], 1);
        }
        __syncthreads();   // protect zxs/red before next group iteration
    }
}

// quantized_z = cb[idx]; quantized_z_st = fl(z + fl(q - z)); float4-vectorized.
// Block 0 computes perplexity (hist complete: approx+rescore2 finished, stream order).
__global__ void scatter_kernel(const float* __restrict__ z, const float* __restrict__ cb,
                               const unsigned* __restrict__ result,
                               const int* __restrict__ hist,
                               float* __restrict__ out) {
    const int o = (blockIdx.x * 256 + threadIdx.x) * 4;    // [0, NTOT), step 4
    const int b = o >> 16, c = (o >> 10) & 63, hw = o & 1023;
    const int n = (b << 10) | hw;
    float q[4];
#pragma unroll
    for (int j = 0; j < 4; ++j) {
        const int k = (int)result[n + j];
        q[j] = cb[k * CDIM + c];
    }
    const float4 zv = *(const float4*)(z + o);
    *(float4*)(out + o) = make_float4(q[0], q[1], q[2], q[3]);
    float4 st;
    st.x = __fadd_rn(zv.x, __fsub_rn(q[0], zv.x));
    st.y = __fadd_rn(zv.y, __fsub_rn(q[1], zv.y));
    st.z = __fadd_rn(zv.z, __fsub_rn(q[2], zv.z));
    st.w = __fadd_rn(zv.w, __fsub_rn(q[3], zv.w));
    *(float4*)(out + NTOT + o) = st;

    if (blockIdx.x == 0) {
        __shared__ double partial[4];
        const int t = threadIdx.x;        // 256 threads x 4 hist entries
        double term = 0.0;
#pragma unroll
        for (int j = 0; j < 4; ++j) {
            const int cnt = hist[t + 256 * j];
            if (cnt > 0) { const double p = (double)cnt / (double)NVEC; term += p * log(p); }
        }
        for (int off = 32; off > 0; off >>= 1) term += __shfl_down(term, off);
        if ((t & 63) == 0) partial[t >> 6] = term;
        __syncthreads();
        if (t == 0) {
            const double sm = partial[0] + partial[1] + partial[2] + partial[3];
            out[2 * NTOT + NVEC] = (float)exp(-sm);
        }
    }
}

extern "C" void kernel_launch(void* const* d_in, const int* in_sizes, int n_in,
                              void* d_out, int out_size, void* d_ws, size_t ws_size,
                              hipStream_t stream) {
    const float* z  = (const float*)d_in[0];   // [64,64,32,32]
    const float* cb = (const float*)d_in[1];   // [1024,64]
    float* out = (float*)d_out;

    char* ws = (char*)d_ws;
    unsigned* result = (unsigned*)ws;                      // 256 KB
    float* se   = (float*)(ws + 524288);
    int*   hist = (int*)(ws + 528384);

    // Transient scratch inside d_out's quantized_z region (overwritten by scatter later).
    char* outB = (char*)d_out;
    _Float16* cbT   = (_Float16*)(outB + (1 << 20));       // 128 KB
    unsigned* wcount = (unsigned*)(outB + 1572864);
    float*    semax4 = (float*)(outB + 1572864 + 16);
    float*    se16   = (float*)(outB + 1572864 + 4096);    // 4 KB
    unsigned* wlist  = (unsigned*)(outB + (2 << 20));      // 256 KB

    float* outIdxF = out + 2 * NTOT;

    prep_kernel<<<4, 256, 0, stream>>>(cb, se, hist, cbT, se16, semax4, wcount);
    approx_kernel<<<NVEC / 32, 256, 0, stream>>>(z, cbT, se16, semax4, result, wlist,
                                                 wcount, outIdxF, hist);
    rescore2_kernel<<<2048, 256, 0, stream>>>(z, cb, se, wlist, wcount, result,
                                              hist, outIdxF);
    scatter_kernel<<<NTOT / 1024, 256, 0, stream>>>(z, cb, result, hist, out);
}

// Round 8
// 188.381 us; speedup vs baseline: 2.1599x; 1.7021x over previous
//
#include <hip/hip_runtime.h>
#include <math.h>

// Problem constants
#define NVEC   65536      // B*H*W
#define CDIM   64
#define KBOOK  1024
#define NTOT   4194304    // B*C*H*W

// d_out layout (float32): [quantized_z: NTOT][quantized_z_st: NTOT][indices: NVEC][perplexity: 1]
// workspace: result u32[NVEC] @0 (256KB) ; float se[KBOOK] @524288 ; int hist[KBOOK] @528384
// TRANSIENT scratch in d_out's quantized_z region (read only BEFORE scatter overwrites):
//   cbT fp16[64 tiles][1024] @out+1MB (128KB) -- fragment-ordered, e scaled x2^14
//   aux @out+1.5MB: wcount u32 @+0 ; semax4 f32[4] @+16 ; se16 f32[1024] @+4096
//   wlist u32[NVEC] @out+2MB (256KB)
//   cbt  f32[64][1024] @out+2.5MB (256KB) -- TRANSPOSED codebook for rescore2 (r7)
// Ordering: prep -> approx(decisive finalized) -> rescore2(flagged, exact full search)
//           -> scatter(+perp). 4 launches.
//
// ROUND-7: rescore2 rebuilt AGAIN.  r6 failure: fully-unrolled q-loop hoisted 64
// float4 cb loads -> 256 VGPR + 168MB scratch spill traffic (rule: bound your
// unrolls), and lane-owns-a-row cb reads were stride-1024B uncoalesced (same bug
// as r1 approx).  Fix: cbt transpose (lane-contiguous k), thread owns k=chunk*256+tid,
// #pragma unroll 2, ~45 VGPR live set, per-thread u64 bests, single end reduce.

typedef _Float16 f16x8 __attribute__((ext_vector_type(8)));
typedef float    f32x4 __attribute__((ext_vector_type(4)));

// prep: zero hist/wcount; exact se (pairwise 8-acc, rn intrinsics); se16 = se*2^14;
// semax4[block] = block-max of se; fragment-ordered fp16 codebook (e*2^14); cbt transpose.
__global__ void prep_kernel(const float* __restrict__ cb, float* __restrict__ se,
                            int* __restrict__ hist, _Float16* __restrict__ cbT,
                            float* __restrict__ se16, float* __restrict__ semax4,
                            unsigned* __restrict__ wcount, float* __restrict__ cbt) {
    __shared__ float lmax[4];
    const int t = blockIdx.x * 256 + threadIdx.x;   // grid 4x256 -> t = codebook row k
    if (t == 0) *wcount = 0u;
    hist[t] = 0;
    const float* row = cb + t * CDIM;
    float r[8];
#pragma unroll
    for (int j = 0; j < 8; ++j) r[j] = __fmul_rn(row[j], row[j]);
#pragma unroll
    for (int i = 8; i < 64; i += 8)
#pragma unroll
        for (int j = 0; j < 8; ++j) r[j] = __fadd_rn(r[j], __fmul_rn(row[i + j], row[i + j]));
    const float sev = __fadd_rn(__fadd_rn(__fadd_rn(r[0], r[1]), __fadd_rn(r[2], r[3])),
                                __fadd_rn(__fadd_rn(r[4], r[5]), __fadd_rn(r[6], r[7])));
    se[t] = sev;
    se16[t] = sev * 16384.0f;            // exact (x2^14)
    float m = sev;
#pragma unroll
    for (int off = 32; off > 0; off >>= 1) m = fmaxf(m, __shfl_xor(m, off));
    if ((threadIdx.x & 63) == 0) lmax[threadIdx.x >> 6] = m;
    __syncthreads();
    if (threadIdx.x == 0)
        semax4[blockIdx.x] = fmaxf(fmaxf(lmax[0], lmax[1]), fmaxf(lmax[2], lmax[3]));
    // transposed codebook for rescore2: cbt[c][k] = cb[k][c]
#pragma unroll
    for (int c = 0; c < 64; ++c) cbt[c * 1024 + t] = row[c];
    // fragment-ordered fp16 codebook, scaled: sub[lane*8+j] = fl16(e*2^14)
    const int tt = t >> 4, la = t & 15;
    _Float16* tb = cbT + (size_t)tt * 1024;        // 2KB tile block (fp16 units)
#pragma unroll
    for (int g = 0; g < 4; ++g)
#pragma unroll
        for (int j = 0; j < 8; ++j) {
            const float e0 = row[8 * g + j] * 16384.0f;        // c in [0,32)
            const float e1 = row[32 + 8 * g + j] * 16384.0f;   // c in [32,64)
            const int lo8 = (g * 16 + la) * 8 + j;             // lane*8 + j
            tb[lo8]       = (_Float16)e0;                      // ah0
            tb[512 + lo8] = (_Float16)e1;                      // ah1
        }
}

// MFMA approx + margin filter (r6 structure, validated absmax 0).  Wave-pair per
// 16-n tile: wave kh handles k-half (32 tiles); exact top-2 merge via LDS.
// Decisive -> finalize; else -> worklist.  THR: worst-case |approx-ref| bound.
__launch_bounds__(256)
__attribute__((amdgpu_waves_per_eu(4, 8)))
__global__ void approx_kernel(const float* __restrict__ z, const _Float16* __restrict__ cbT,
                              const float* __restrict__ se16, const float* __restrict__ semax4,
                              unsigned* __restrict__ result, unsigned* __restrict__ wlist,
                              unsigned* __restrict__ wcount, float* __restrict__ outIdxF,
                              int* __restrict__ hist) {
    __shared__ unsigned m1[4][16], m2[4][16];
    const int tid = threadIdx.x;
    const int w = tid >> 6;           // wave in block
    const int l = tid & 63;           // lane
    const int la = l & 15;            // D-col (n) offset / A-row offset
    const int g  = l >> 4;            // lane group
    const int pair = w >> 1;          // n-tile pair in block
    const int kh = w & 1;             // k-half
    const int n = blockIdx.x * 32 + pair * 16 + la;
    const int b = n >> 10, hw = n & 1023;
    const float* zb = z + (size_t)b * (CDIM * 1024) + hw;   // + c*1024

    f16x8 mh0, mh1;
    float psum = 0.0f;
#pragma unroll
    for (int j = 0; j < 8; ++j) {
        {   float zc = zb[(g * 8 + j) * 1024];
            mh0[j] = (_Float16)(-2.0f * zc);
            psum = fmaf(zc, zc, psum); }
        {   float zc = zb[(32 + g * 8 + j) * 1024];
            mh1[j] = (_Float16)(-2.0f * zc);
            psum = fmaf(zc, zc, psum); }
    }

    unsigned u1k = 0xFFFFFFFFu, u2k = 0xFFFFFFFFu;
    const int kv = g * 4;                          // D-row base for this lane
    const _Float16* tbase = cbT + (size_t)l * 8;   // lane offset inside each sub-block

#define DECL_SLOT(s) f16x8 ah0_##s, ah1_##s; f32x4 se_##s;
    DECL_SLOT(a) DECL_SLOT(b)
#undef DECL_SLOT

#define LOADT(s, ttv) { const int t_ = (ttv) & 63;                       \
        const _Float16* p_ = tbase + (size_t)t_ * 1024;                  \
        ah0_##s = *(const f16x8*)(p_);                                   \
        ah1_##s = *(const f16x8*)(p_ + 512);                             \
        se_##s  = *(const f32x4*)(se16 + t_ * 16 + kv); }

#define PINS(acc_, r_, k0_) {                                            \
        unsigned ub = __float_as_uint(acc_[r_]);                         \
        ub = ((int)ub < 0) ? ~ub : (ub | 0x80000000u);                   \
        const unsigned key = (ub & 0xFFFFFC00u) | (unsigned)((k0_) + kv + (r_)); \
        const unsigned mx = (u1k > key) ? u1k : key;                     \
        u1k = (u1k < key) ? u1k : key;                                   \
        u2k = (u2k < mx) ? u2k : mx; }

#define COMPT(s, ttv) { const int k0_ = (ttv) * 16;                      \
        f32x4 acc = se_##s;                                              \
        acc = __builtin_amdgcn_mfma_f32_16x16x32_f16(ah0_##s, mh0, acc, 0, 0, 0); \
        acc = __builtin_amdgcn_mfma_f32_16x16x32_f16(ah1_##s, mh1, acc, 0, 0, 0); \
        PINS(acc, 0, k0_) PINS(acc, 1, k0_) PINS(acc, 2, k0_) PINS(acc, 3, k0_) }

    const int t0 = kh * 32;
    LOADT(a, t0)
    for (int tt = t0; tt < t0 + 32; tt += 2) {
        LOADT(b, tt + 1)
        COMPT(a, tt)
        LOADT(a, tt + 2)
        COMPT(b, tt + 1)
    }
#undef LOADT
#undef PINS
#undef COMPT

    // wave-level exact top-2 + full sum(z^2) across the 4 same-n lane groups
#pragma unroll
    for (int off = 16; off <= 32; off <<= 1) {
        const unsigned p1 = __shfl_xor(u1k, off);
        const unsigned p2 = __shfl_xor(u2k, off);
        psum += __shfl_xor(psum, off);
        const unsigned mx = (u1k > p1) ? u1k : p1;
        u1k = (u1k < p1) ? u1k : p1;
        const unsigned mm = (u2k < p2) ? u2k : p2;
        u2k = (mm < mx) ? mm : mx;
    }

    if (l < 16) { m1[w][la] = u1k; m2[w][la] = u2k; }
    __syncthreads();

    if (kh == 0 && l < 16) {
        const unsigned o1 = m1[w + 1][la], o2 = m2[w + 1][la];
        const unsigned mx = (u1k > o1) ? u1k : o1;
        const unsigned u1 = (u1k < o1) ? u1k : o1;
        unsigned u2 = (u2k < o2) ? u2k : o2;
        u2 = (u2 < mx) ? u2 : mx;

        const float sx = psum;
        const float srt = sqrtf(fmaxf(fmaxf(semax4[0], semax4[1]),
                                      fmaxf(semax4[2], semax4[3]))) * 1.0001f;
        // worst-case deviation bound (scaled x2^14 space), x1.25 slack (r5-validated)
        const float THR = 60.2f * sqrtf(sx) * srt + 1.97e-2f * sx + 0.165f;
        const unsigned x1 = u1 & 0xFFFFFC00u, x2 = u2 & 0xFFFFFC00u;
        const float f1 = __uint_as_float((x1 & 0x80000000u) ? (x1 & 0x7FFFFFFFu) : ~x1);
        const float f2 = __uint_as_float((x2 & 0x80000000u) ? (x2 & 0x7FFFFFFFu) : ~x2);
        const int k1 = (int)(u1 & 1023u);
        if (f2 - f1 > THR) {     // unique exact argmin guaranteed
            result[n] = (unsigned)k1;
            outIdxF[n] = (float)k1;
            atomicAdd(&hist[k1], 1);
        } else {
            const unsigned widx = atomicAdd(wcount, 1u);
            wlist[widx] = (unsigned)n;
        }
    }
}

// Exact full 1024-k search for flagged n.  Block per 4 worklist items, grid-stride.
// zx/sx staged in LDS (bit-identical reference chain).  Thread owns k=chunk*256+tid
// (4 chunks): cbt[c*1024+k] reads are lane-contiguous (coalesced, L2-hot).
// Per-c: 1 e-scalar + 4 LDS-broadcast z reads + 4 fmaf (ascending c = ref order).
// u64 ordered-key (d bits || k) min -> first-min semantics.
__launch_bounds__(256)
__global__ void rescore2_kernel(const float* __restrict__ z, const float* __restrict__ cbt,
                                const float* __restrict__ se,
                                const unsigned* __restrict__ wlist,
                                const unsigned* __restrict__ wcount,
                                unsigned* __restrict__ result, int* __restrict__ hist,
                                float* __restrict__ outIdxF) {
    __shared__ float zxs[4][64];
    __shared__ float rres[4][8];
    __shared__ float sxs[4];
    __shared__ unsigned long long red[4][4];   // [wave][n-slot]
    const int cnt = (int)*wcount;
    const int tid = threadIdx.x;
    const int wv = tid >> 6, l = tid & 63;

    for (int base = blockIdx.x * 4; base < cnt; base += gridDim.x * 4) {
        // ---- stage z (thread = ns*64 + c) ----
        const int ns = tid >> 6, c = tid & 63;
        const int item = base + ns;
        const int n = (int)wlist[(item < cnt) ? item : base];   // dup-safe tail
        {
            const int b = n >> 10, hw = n & 1023;
            const float zc = z[(size_t)b * (CDIM * 1024) + c * 1024 + hw];
            zxs[ns][c] = zc + zc;                // exact 2z
        }
        __syncthreads();
        if (c < 8) {                             // 8 residue chains (ref-exact)
            const float z0 = zxs[ns][c] * 0.5f;  // exact recover z
            float rr = __fmul_rn(z0, z0);
            for (int i = c + 8; i < 64; i += 8) {
                const float zi = zxs[ns][i] * 0.5f;
                rr = __fadd_rn(rr, __fmul_rn(zi, zi));
            }
            rres[ns][c] = rr;
        }
        __syncthreads();
        if (c == 0) {
            const float* r = rres[ns];
            sxs[ns] = __fadd_rn(__fadd_rn(__fadd_rn(r[0], r[1]), __fadd_rn(r[2], r[3])),
                                __fadd_rn(__fadd_rn(r[4], r[5]), __fadd_rn(r[6], r[7])));
        }
        __syncthreads();

        // ---- k sweep: thread owns k = chunk*256 + tid ----
        unsigned long long best0 = ~0ull, best1 = ~0ull, best2 = ~0ull, best3 = ~0ull;
        for (int chunk = 0; chunk < 4; ++chunk) {       // NOT unrolled: bounded live set
            const int k = (chunk << 8) + tid;
            float a0 = 0.f, a1 = 0.f, a2 = 0.f, a3 = 0.f;
#pragma unroll 2
            for (int c4 = 0; c4 < 16; ++c4) {
                const float e0 = cbt[(4 * c4 + 0) * 1024 + k];   // lane-contiguous
                const float e1 = cbt[(4 * c4 + 1) * 1024 + k];
                const float e2 = cbt[(4 * c4 + 2) * 1024 + k];
                const float e3 = cbt[(4 * c4 + 3) * 1024 + k];
                const f32x4 z0 = *(const f32x4*)&zxs[0][4 * c4]; // LDS broadcast
                const f32x4 z1 = *(const f32x4*)&zxs[1][4 * c4];
                const f32x4 z2 = *(const f32x4*)&zxs[2][4 * c4];
                const f32x4 z3 = *(const f32x4*)&zxs[3][4 * c4];
                a0 = fmaf(z0[0], e0, a0); a0 = fmaf(z0[1], e1, a0);
                a0 = fmaf(z0[2], e2, a0); a0 = fmaf(z0[3], e3, a0);
                a1 = fmaf(z1[0], e0, a1); a1 = fmaf(z1[1], e1, a1);
                a1 = fmaf(z1[2], e2, a1); a1 = fmaf(z1[3], e3, a1);
                a2 = fmaf(z2[0], e0, a2); a2 = fmaf(z2[1], e1, a2);
                a2 = fmaf(z2[2], e2, a2); a2 = fmaf(z2[3], e3, a2);
                a3 = fmaf(z3[0], e0, a3); a3 = fmaf(z3[1], e1, a3);
                a3 = fmaf(z3[2], e2, a3); a3 = fmaf(z3[3], e3, a3);
            }
            const float sek = se[k];
#define DKEY(ai, bi) { const float d_ = __fsub_rn(__fadd_rn(sxs[bi], sek), ai);    \
        unsigned ob = __float_as_uint(d_);                                         \
        ob = (ob & 0x80000000u) ? ~ob : (ob | 0x80000000u);                        \
        const unsigned long long key = ((unsigned long long)ob << 32) | (unsigned)k; \
        if (key < best##bi) best##bi = key; }
            DKEY(a0, 0) DKEY(a1, 1) DKEY(a2, 2) DKEY(a3, 3)
#undef DKEY
        }

        // ---- reduce: per n-slot u64 key min (wave shfl, then cross-wave LDS) ----
#define WRED(bi) {                                                       \
        unsigned long long b_ = best##bi;                                \
        _Pragma("unroll")                                                \
        for (int off = 1; off <= 32; off <<= 1) {                        \
            const unsigned long long o = __shfl_xor(b_, off);            \
            if (o < b_) b_ = o;                                          \
        }                                                                \
        if (l == 0) red[wv][bi] = b_; }
        WRED(0) WRED(1) WRED(2) WRED(3)
#undef WRED
        __syncthreads();
        if (tid < 4 && base + tid < cnt) {
            unsigned long long bb = red[0][tid];
            if (red[1][tid] < bb) bb = red[1][tid];
            if (red[2][tid] < bb) bb = red[2][tid];
            if (red[3][tid] < bb) bb = red[3][tid];
            const int n2 = (int)wlist[base + tid];
            const int kb = (int)(bb & 0xFFFFFFFFull);
            result[n2] = (unsigned)kb;
            outIdxF[n2] = (float)kb;
            atomicAdd(&hist[kb], 1);
        }
        __syncthreads();   // protect zxs/red before next group iteration
    }
}

// quantized_z = cb[idx]; quantized_z_st = fl(z + fl(q - z)); float4-vectorized.
// Block 0 computes perplexity (hist complete: approx+rescore2 finished, stream order).
__global__ void scatter_kernel(const float* __restrict__ z, const float* __restrict__ cb,
                               const unsigned* __restrict__ result,
                               const int* __restrict__ hist,
                               float* __restrict__ out) {
    const int o = (blockIdx.x * 256 + threadIdx.x) * 4;    // [0, NTOT), step 4
    const int b = o >> 16, c = (o >> 10) & 63, hw = o & 1023;
    const int n = (b << 10) | hw;
    float q[4];
#pragma unroll
    for (int j = 0; j < 4; ++j) {
        const int k = (int)result[n + j];
        q[j] = cb[k * CDIM + c];
    }
    const float4 zv = *(const float4*)(z + o);
    *(float4*)(out + o) = make_float4(q[0], q[1], q[2], q[3]);
    float4 st;
    st.x = __fadd_rn(zv.x, __fsub_rn(q[0], zv.x));
    st.y = __fadd_rn(zv.y, __fsub_rn(q[1], zv.y));
    st.z = __fadd_rn(zv.z, __fsub_rn(q[2], zv.z));
    st.w = __fadd_rn(zv.w, __fsub_rn(q[3], zv.w));
    *(float4*)(out + NTOT + o) = st;

    if (blockIdx.x == 0) {
        __shared__ double partial[4];
        const int t = threadIdx.x;        // 256 threads x 4 hist entries
        double term = 0.0;
#pragma unroll
        for (int j = 0; j < 4; ++j) {
            const int cnt = hist[t + 256 * j];
            if (cnt > 0) { const double p = (double)cnt / (double)NVEC; term += p * log(p); }
        }
        for (int off = 32; off > 0; off >>= 1) term += __shfl_down(term, off);
        if ((t & 63) == 0) partial[t >> 6] = term;
        __syncthreads();
        if (t == 0) {
            const double sm = partial[0] + partial[1] + partial[2] + partial[3];
            out[2 * NTOT + NVEC] = (float)exp(-sm);
        }
    }
}

extern "C" void kernel_launch(void* const* d_in, const int* in_sizes, int n_in,
                              void* d_out, int out_size, void* d_ws, size_t ws_size,
                              hipStream_t stream) {
    const float* z  = (const float*)d_in[0];   // [64,64,32,32]
    const float* cb = (const float*)d_in[1];   // [1024,64]
    float* out = (float*)d_out;

    char* ws = (char*)d_ws;
    unsigned* result = (unsigned*)ws;                      // 256 KB
    float* se   = (float*)(ws + 524288);
    int*   hist = (int*)(ws + 528384);

    // Transient scratch inside d_out's quantized_z region (overwritten by scatter later).
    char* outB = (char*)d_out;
    _Float16* cbT   = (_Float16*)(outB + (1 << 20));       // 128 KB
    unsigned* wcount = (unsigned*)(outB + 1572864);
    float*    semax4 = (float*)(outB + 1572864 + 16);
    float*    se16   = (float*)(outB + 1572864 + 4096);    // 4 KB
    unsigned* wlist  = (unsigned*)(outB + (2 << 20));      // 256 KB
    float*    cbt    = (float*)(outB + (2 << 20) + (512 << 10));   // 256 KB @out+2.5MB

    float* outIdxF = out + 2 * NTOT;

    prep_kernel<<<4, 256, 0, stream>>>(cb, se, hist, cbT, se16, semax4, wcount, cbt);
    approx_kernel<<<NVEC / 32, 256, 0, stream>>>(z, cbT, se16, semax4, result, wlist,
                                                 wcount, outIdxF, hist);
    rescore2_kernel<<<1024, 256, 0, stream>>>(z, cbt, se, wlist, wcount, result,
                                              hist, outIdxF);
    scatter_kernel<<<NTOT / 1024, 256, 0, stream>>>(z, cb, result, hist, out);
}